// Round 1
// baseline (637.652 us; speedup 1.0000x reference)
//
#include <hip/hip_runtime.h>
#include <math.h>

// ---------------- problem constants ----------------
constexpr int BN = 65536;   // batch
constexpr int DK = 512;     // feature dim
constexpr int CN = 50;      // classes
constexpr int FILTK = 10;   // per-class top-K
constexpr int BR = 64;      // rows per GEMM block
constexpr int KC = 32;      // K chunk
constexpr int AS = 36;      // LDS stride for A tile (floats)
constexpr int BS = 68;      // LDS stride for B tile (floats)

// ---------------- workspace layout (u32 words) ----------------
constexpr int W_HISTA   = 0;                    // 65536
constexpr int W_HISTBLO = 65536;                // 65536
constexpr int W_HISTBHI = 131072;               // 65536
constexpr int W_CACC    = 196608;               // 50*512 = 25600
constexpr int W_SC      = 222208;               // 64
constexpr int ZERO_WORDS= 222272;               // everything above gets zeroed each call
constexpr int W_ENT     = ZERO_WORDS;           // BN
constexpr int W_PMAX    = W_ENT  + BN;
constexpr int W_YHAT    = W_PMAX + BN;
constexpr int W_CONS    = W_YHAT + BN;
constexpr int W_NORM    = W_CONS + BN;
constexpr int W_LAB0    = W_NORM + BN;          // 64
constexpr int W_ENT0    = W_LAB0 + 64;
constexpr int W_CONF0   = W_ENT0 + 64;
constexpr int W_WNORM   = W_CONF0 + 64;
constexpr int LE_CAP    = BN + 64;
constexpr int W_LECLS   = W_WNORM + 64;
constexpr int W_LEENT   = W_LECLS  + LE_CAP;
constexpr int W_LECONF  = W_LEENT  + LE_CAP;
constexpr int W_LEORD   = W_LECONF + LE_CAP;
constexpr int W_LESRC   = W_LEORD  + LE_CAP;
constexpr int W_LEW     = W_LESRC  + LE_CAP;

struct Scalars {
    float    sum_ent;   // atomic accum
    float    mean;
    float    conf_thr;
    float    frac;
    int      klo;
    int      khi;
    int      binlo;
    int      rlo;
    int      binhi;
    int      rhi;
    float    thr;
    unsigned cnt;       // atomic accepted count
};

// monotone float<->u32 key (total order matching float compare)
__device__ __forceinline__ unsigned fkey(float f) {
    unsigned u = __float_as_uint(f);
    return (u & 0x80000000u) ? ~u : (u | 0x80000000u);
}
__device__ __forceinline__ float funkey(unsigned u) {
    return (u & 0x80000000u) ? __uint_as_float(u & 0x7fffffffu) : __uint_as_float(~u);
}

// ---------------- kernels ----------------

__global__ void zero_kernel(unsigned* __restrict__ p, int n) {
    for (int i = blockIdx.x * blockDim.x + threadIdx.x; i < n; i += gridDim.x * blockDim.x)
        p[i] = 0u;
}

// warmup: wl = W@W.T + b  -> lab0, ent0, conf0; also ||W_i||
// grid 50 blocks x 64 threads (one wave per row)
__global__ void warm_kernel(const float* __restrict__ W, const float* __restrict__ bias,
                            int* __restrict__ lab0, float* __restrict__ ent0,
                            float* __restrict__ conf0, float* __restrict__ wnorm) {
    __shared__ float wrow[DK];
    const int i = blockIdx.x, l = threadIdx.x;
    float4 v0 = *(const float4*)(W + i * DK + l * 4);
    float4 v1 = *(const float4*)(W + i * DK + 256 + l * 4);
    *(float4*)(wrow + l * 4) = v0;
    *(float4*)(wrow + 256 + l * 4) = v1;
    float sq = v0.x*v0.x + v0.y*v0.y + v0.z*v0.z + v0.w*v0.w
             + v1.x*v1.x + v1.y*v1.y + v1.z*v1.z + v1.w*v1.w;
    #pragma unroll
    for (int m = 1; m < 64; m <<= 1) sq += __shfl_xor(sq, m);
    if (l == 0) wnorm[i] = sqrtf(sq);
    __syncthreads();

    float dot = -INFINITY;
    int   ai  = 0x7fffffff;
    if (l < CN) {
        const float* wj = W + l * DK;
        float d2 = 0.f;
        for (int d = 0; d < DK; d += 4) {
            float4 a  = *(const float4*)(wrow + d);
            float4 b4 = *(const float4*)(wj + d);
            d2 = fmaf(a.x, b4.x, fmaf(a.y, b4.y, fmaf(a.z, b4.z, fmaf(a.w, b4.w, d2))));
        }
        dot = d2 + bias[l];
        ai  = l;
    }
    float mx = dot; int am = ai;
    #pragma unroll
    for (int m = 32; m >= 1; m >>= 1) {
        float o = __shfl_xor(mx, m); int oi = __shfl_xor(am, m);
        if (o > mx || (o == mx && oi < am)) { mx = o; am = oi; }
    }
    float e = 0.f, te = 0.f;
    if (l < CN) { e = expf(dot - mx); te = e * (dot - mx); }
    #pragma unroll
    for (int m = 1; m < 64; m <<= 1) { e += __shfl_xor(e, m); te += __shfl_xor(te, m); }
    if (l == 0) {
        lab0[i]  = am;
        ent0[i]  = logf(e) - te / e;
        conf0[i] = 1.f / e;
    }
}

// Tiled skinny GEMM: (BN x DK) @ (CN x DK)^T, CN padded to 64 in-tile.
// MODE 0: logits epilogue (softmax stats) + fused row-norm accumulation
// MODE 1: sim epilogue (out = 20 * dot / max(norm,eps))
template <int MODE>
__global__ void gemm_kernel(const float* __restrict__ A, const float* __restrict__ Bm,
                            const float* __restrict__ bias,
                            float* __restrict__ ent, float* __restrict__ pmaxA,
                            int* __restrict__ yhat, float* __restrict__ rnorm,
                            const float* __restrict__ in_norm, float* __restrict__ outp) {
    __shared__ float smem[BR * AS + KC * BS];  // 17.9 KB
    float* Af = smem;
    float* Bw = smem + BR * AS;
    const int t = threadIdx.x;
    const int tx = t & 15, ty = t >> 4;
    const int row0 = blockIdx.x * BR;
    const int srow = t >> 3, sf4 = t & 7;

    float acc[4][4];
    #pragma unroll
    for (int q = 0; q < 4; q++)
        #pragma unroll
        for (int p = 0; p < 4; p++) acc[q][p] = 0.f;
    float sq0 = 0.f, sq1 = 0.f;

    for (int k0 = 0; k0 < DK; k0 += KC) {
        __syncthreads();
        // stage A tile (64 x 32)
        float4 va0 = *(const float4*)(A + (row0 + srow) * DK + k0 + sf4 * 4);
        float4 va1 = *(const float4*)(A + (row0 + srow + 32) * DK + k0 + sf4 * 4);
        *(float4*)(Af + srow * AS + sf4 * 4) = va0;
        *(float4*)(Af + (srow + 32) * AS + sf4 * 4) = va1;
        if (MODE == 0) {
            sq0 += va0.x*va0.x + va0.y*va0.y + va0.z*va0.z + va0.w*va0.w;
            sq1 += va1.x*va1.x + va1.y*va1.y + va1.z*va1.z + va1.w*va1.w;
        }
        // stage B tile transposed: Bw[kk][c]
        #pragma unroll
        for (int h = 0; h < 2; h++) {
            int c = (t >> 3) + h * 32;
            float4 vb = make_float4(0.f, 0.f, 0.f, 0.f);
            if (c < CN) vb = *(const float4*)(Bm + c * DK + k0 + sf4 * 4);
            Bw[(sf4 * 4 + 0) * BS + c] = vb.x;
            Bw[(sf4 * 4 + 1) * BS + c] = vb.y;
            Bw[(sf4 * 4 + 2) * BS + c] = vb.z;
            Bw[(sf4 * 4 + 3) * BS + c] = vb.w;
        }
        __syncthreads();
        #pragma unroll
        for (int kk = 0; kk < KC; kk += 4) {
            float4 a[4], bb[4];
            #pragma unroll
            for (int q = 0; q < 4; q++) a[q] = *(const float4*)(Af + (ty * 4 + q) * AS + kk);
            #pragma unroll
            for (int j = 0; j < 4; j++) bb[j] = *(const float4*)(Bw + (kk + j) * BS + tx * 4);
            #pragma unroll
            for (int q = 0; q < 4; q++) {
                float aq[4] = {a[q].x, a[q].y, a[q].z, a[q].w};
                #pragma unroll
                for (int j = 0; j < 4; j++) {
                    acc[q][0] = fmaf(aq[j], bb[j].x, acc[q][0]);
                    acc[q][1] = fmaf(aq[j], bb[j].y, acc[q][1]);
                    acc[q][2] = fmaf(aq[j], bb[j].z, acc[q][2]);
                    acc[q][3] = fmaf(aq[j], bb[j].w, acc[q][3]);
                }
            }
        }
    }

    if (MODE == 0) {
        // finish row norms (8 consecutive threads share a row)
        float s0 = sq0, s1 = sq1;
        #pragma unroll
        for (int m = 1; m < 8; m <<= 1) { s0 += __shfl_xor(s0, m); s1 += __shfl_xor(s1, m); }
        if (sf4 == 0) { rnorm[row0 + srow] = sqrtf(s0); rnorm[row0 + srow + 32] = sqrtf(s1); }
        __syncthreads();
        float* L = smem;  // reuse as 64 x 52 logits
        #pragma unroll
        for (int q = 0; q < 4; q++) {
            int r = ty * 4 + q;
            #pragma unroll
            for (int p = 0; p < 4; p++) {
                int c = tx * 4 + p;
                if (c < CN) L[r * 52 + c] = acc[q][p] + bias[c];
            }
        }
        __syncthreads();
        if (t < BR) {
            const float* Lr = L + t * 52;
            float mx = Lr[0]; int am = 0;
            for (int j = 1; j < CN; j++) { float v = Lr[j]; if (v > mx) { mx = v; am = j; } }
            float s = 0.f, tt = 0.f;
            for (int j = 0; j < CN; j++) {
                float d = Lr[j] - mx;
                float e = expf(d);
                s += e; tt += e * d;
            }
            ent  [row0 + t] = logf(s) - tt / s;
            pmaxA[row0 + t] = 1.f / s;
            yhat [row0 + t] = am;
        }
    } else {
        #pragma unroll
        for (int q = 0; q < 4; q++) {
            int r = row0 + ty * 4 + q;
            float sc = 20.f / fmaxf(in_norm[r], 1e-12f);
            #pragma unroll
            for (int p = 0; p < 4; p++) {
                int c = tx * 4 + p;
                if (c < CN) outp[r * CN + c] = acc[q][p] * sc;
            }
        }
    }
}

// dual-view argmax consistency: one wave per row
__global__ void cons_kernel(const float* __restrict__ raw, const float* __restrict__ aug,
                            unsigned* __restrict__ cons) {
    const int w = threadIdx.x >> 6, l = threadIdx.x & 63;
    const int row = blockIdx.x * 4 + w;
    float vr = (l < CN) ? raw[row * CN + l] : -INFINITY;
    float va = (l < CN) ? aug[row * CN + l] : -INFINITY;
    int ar = (l < CN) ? l : 0x7fffffff;
    int aa = ar;
    #pragma unroll
    for (int m = 32; m >= 1; m >>= 1) {
        float o = __shfl_xor(vr, m); int oi = __shfl_xor(ar, m);
        if (o > vr || (o == vr && oi < ar)) { vr = o; ar = oi; }
        o = __shfl_xor(va, m); oi = __shfl_xor(aa, m);
        if (o > va || (o == va && oi < aa)) { va = o; aa = oi; }
    }
    if (l == 0) cons[row] = (ar == aa) ? 1u : 0u;
}

__global__ void mean_kernel(const float* __restrict__ ent, Scalars* sc) {
    int i = blockIdx.x * blockDim.x + threadIdx.x;
    float v = (i < BN) ? ent[i] : 0.f;
    #pragma unroll
    for (int m = 1; m < 64; m <<= 1) v += __shfl_xor(v, m);
    __shared__ float sb[4];
    int l = threadIdx.x & 63, w = threadIdx.x >> 6;
    if (l == 0) sb[w] = v;
    __syncthreads();
    if (threadIdx.x == 0) atomicAdd(&sc->sum_ent, sb[0] + sb[1] + sb[2] + sb[3]);
}

__global__ void setup_kernel(Scalars* sc) {
    float m = sc->sum_ent / (float)BN;
    sc->mean = m;
    float q = (m >= 0.45f) ? 0.25f : ((m >= 0.38f) ? 0.30f : 0.40f);
    sc->conf_thr = (m >= 0.45f) ? 0.72f : 0.62f;
    float pos = q * (float)(BN - 1);
    float lo  = floorf(pos);
    int klo = (int)lo;
    int khi = klo + 1; if (khi > BN - 1) khi = BN - 1;
    sc->frac = pos - lo;
    sc->klo = klo; sc->khi = khi;
}

__global__ void histA_kernel(const float* __restrict__ ent, unsigned* __restrict__ histA) {
    int i = blockIdx.x * blockDim.x + threadIdx.x;
    if (i < BN) atomicAdd(&histA[fkey(ent[i]) >> 16], 1u);
}

__global__ void scanA_kernel(const unsigned* __restrict__ histA, Scalars* sc) {
    __shared__ unsigned ps[1024];
    int t = threadIdx.x;
    unsigned s = 0;
    for (int j = 0; j < 64; j++) s += histA[t * 64 + j];
    ps[t] = s;
    __syncthreads();
    if (t == 0) {
        for (int pass = 0; pass < 2; pass++) {
            unsigned k = (pass == 0) ? (unsigned)sc->klo : (unsigned)sc->khi;
            unsigned cum = 0; int ch = 1023;
            for (int c = 0; c < 1024; c++) { unsigned pc = ps[c]; if (cum + pc > k) { ch = c; break; } cum += pc; }
            int bin = ch * 64 + 63;
            for (int j = 0; j < 64; j++) { unsigned h = histA[ch * 64 + j]; if (cum + h > k) { bin = ch * 64 + j; break; } cum += h; }
            if (pass == 0) { sc->binlo = bin; sc->rlo = (int)(k - cum); }
            else           { sc->binhi = bin; sc->rhi = (int)(k - cum); }
        }
    }
}

__global__ void histB_kernel(const float* __restrict__ ent, const Scalars* sc,
                             unsigned* __restrict__ hlo, unsigned* __restrict__ hhi) {
    int i = blockIdx.x * blockDim.x + threadIdx.x;
    if (i >= BN) return;
    unsigned u = fkey(ent[i]);
    unsigned h16 = u >> 16;
    if (h16 == (unsigned)sc->binlo) atomicAdd(&hlo[u & 0xffffu], 1u);
    if (h16 == (unsigned)sc->binhi) atomicAdd(&hhi[u & 0xffffu], 1u);
}

__global__ void scanB_kernel(const unsigned* __restrict__ hlo, const unsigned* __restrict__ hhi,
                             Scalars* sc) {
    __shared__ unsigned ps[1024];
    int t = threadIdx.x;
    for (int pass = 0; pass < 2; pass++) {
        const unsigned* h = pass ? hhi : hlo;
        unsigned s = 0;
        for (int j = 0; j < 64; j++) s += h[t * 64 + j];
        ps[t] = s;
        __syncthreads();
        if (t == 0) {
            unsigned k = pass ? (unsigned)sc->rhi : (unsigned)sc->rlo;
            unsigned cum = 0; int ch = 1023;
            for (int c = 0; c < 1024; c++) { unsigned pc = ps[c]; if (cum + pc > k) { ch = c; break; } cum += pc; }
            int bin = ch * 64 + 63;
            for (int j = 0; j < 64; j++) { unsigned hh = h[ch * 64 + j]; if (cum + hh > k) { bin = ch * 64 + j; break; } cum += hh; }
            unsigned u = ((unsigned)(pass ? sc->binhi : sc->binlo) << 16) | (unsigned)bin;
            float val = funkey(u);
            if (pass == 0) sc->thr = val;
            else           sc->thr = sc->thr * (1.f - sc->frac) + val * sc->frac;
        }
        __syncthreads();
    }
}

__global__ void compact_kernel(const float* __restrict__ ent, const float* __restrict__ pmaxA,
                               const int* __restrict__ yhat, const unsigned* __restrict__ cons,
                               const int* __restrict__ lab0, const float* __restrict__ ent0,
                               const float* __restrict__ conf0, Scalars* sc,
                               int* le_cls, float* le_ent, float* le_conf, int* le_ord, int* le_src) {
    int i = blockIdx.x * blockDim.x + threadIdx.x;
    if (i < CN) {  // warmup entries occupy fixed slots 0..49
        le_cls[i] = lab0[i]; le_ent[i] = ent0[i]; le_conf[i] = conf0[i];
        le_ord[i] = i; le_src[i] = i;
    }
    if (i >= BN) return;
    bool m = (ent[i] <= sc->thr) && (cons[i] != 0u) && (pmaxA[i] >= sc->conf_thr);
    if (m) {
        int pos = (int)atomicAdd(&sc->cnt, 1u);
        int e = CN + pos;
        le_cls[e] = yhat[i]; le_ent[e] = ent[i]; le_conf[e] = pmaxA[i];
        le_ord[e] = CN + i;  le_src[e] = i;
    }
}

// per-class rank-by-entropy; keep if rank < FILTK.  O(M^2), M is small in practice.
__global__ void topk_kernel(const Scalars* sc, const int* __restrict__ le_cls,
                            const float* __restrict__ le_ent, const float* __restrict__ le_conf,
                            const int* __restrict__ le_ord, float* __restrict__ le_w) {
    int M = CN + (int)sc->cnt;
    for (int e = blockIdx.x * blockDim.x + threadIdx.x; e < M; e += gridDim.x * blockDim.x) {
        int c = le_cls[e]; float v = le_ent[e]; int o = le_ord[e];
        int cnt = 0;
        for (int e2 = 0; e2 < M && cnt < FILTK; e2++) {
            if (le_cls[e2] == c) {
                float v2 = le_ent[e2];
                if (v2 < v || (v2 == v && le_ord[e2] < o)) cnt++;
            }
        }
        le_w[e] = (cnt < FILTK) ? fmaxf(le_conf[e], 1e-6f) : 0.f;
    }
}

// centroid accumulation: cacc[c] += w * support_row / max(||row||, eps)
__global__ void cacc_kernel(const Scalars* sc, const int* __restrict__ le_cls,
                            const float* __restrict__ le_w, const int* __restrict__ le_src,
                            const float* __restrict__ W, const float* __restrict__ feat,
                            const float* __restrict__ wnorm, const float* __restrict__ rnorm,
                            float* __restrict__ cacc) {
    int M = CN + (int)sc->cnt;
    for (int e = blockIdx.x; e < M; e += gridDim.x) {
        float w = le_w[e];
        if (w <= 0.f) continue;
        int src = le_src[e];
        const float* rowp = (e < CN) ? (W + src * DK) : (feat + (size_t)src * DK);
        float nrm = (e < CN) ? wnorm[src] : rnorm[src];
        float k = w / fmaxf(nrm, 1e-12f);
        int c = le_cls[e];
        for (int d = threadIdx.x; d < DK; d += blockDim.x)
            atomicAdd(&cacc[c * DK + d], k * rowp[d]);
    }
}

__global__ void cnorm_kernel(float* __restrict__ cacc) {
    int c = blockIdx.x;
    float s = 0.f;
    for (int d = threadIdx.x; d < DK; d += blockDim.x) { float v = cacc[c * DK + d]; s += v * v; }
    #pragma unroll
    for (int m = 1; m < 64; m <<= 1) s += __shfl_xor(s, m);
    __shared__ float sb[4];
    int l = threadIdx.x & 63, w = threadIdx.x >> 6;
    if (l == 0) sb[w] = s;
    __syncthreads();
    float inv = 1.f / fmaxf(sqrtf(sb[0] + sb[1] + sb[2] + sb[3]), 1e-12f);
    for (int d = threadIdx.x; d < DK; d += blockDim.x) cacc[c * DK + d] *= inv;
}

// ---------------- launch ----------------
extern "C" void kernel_launch(void* const* d_in, const int* in_sizes, int n_in,
                              void* d_out, int out_size, void* d_ws, size_t ws_size,
                              hipStream_t stream) {
    const float* feat = (const float*)d_in[0];
    const float* lraw = (const float*)d_in[1];
    const float* laug = (const float*)d_in[2];
    const float* W    = (const float*)d_in[3];
    const float* bias = (const float*)d_in[4];
    float* out = (float*)d_out;

    unsigned* wsw    = (unsigned*)d_ws;
    unsigned* histA  = wsw + W_HISTA;
    unsigned* histBl = wsw + W_HISTBLO;
    unsigned* histBh = wsw + W_HISTBHI;
    float*    cacc   = (float*)(wsw + W_CACC);
    Scalars*  sc     = (Scalars*)(wsw + W_SC);
    float*    ent    = (float*)(wsw + W_ENT);
    float*    pmaxA  = (float*)(wsw + W_PMAX);
    int*      yhat   = (int*)(wsw + W_YHAT);
    unsigned* cons   = wsw + W_CONS;
    float*    rnorm  = (float*)(wsw + W_NORM);
    int*      lab0   = (int*)(wsw + W_LAB0);
    float*    ent0   = (float*)(wsw + W_ENT0);
    float*    conf0  = (float*)(wsw + W_CONF0);
    float*    wnorm  = (float*)(wsw + W_WNORM);
    int*      le_cls = (int*)(wsw + W_LECLS);
    float*    le_ent = (float*)(wsw + W_LEENT);
    float*    le_conf= (float*)(wsw + W_LECONF);
    int*      le_ord = (int*)(wsw + W_LEORD);
    int*      le_src = (int*)(wsw + W_LESRC);
    float*    le_w   = (float*)(wsw + W_LEW);

    zero_kernel<<<256, 256, 0, stream>>>(wsw, ZERO_WORDS);
    warm_kernel<<<CN, 64, 0, stream>>>(W, bias, lab0, ent0, conf0, wnorm);
    gemm_kernel<0><<<BN / BR, 256, 0, stream>>>(feat, W, bias, ent, pmaxA, yhat, rnorm, nullptr, nullptr);
    cons_kernel<<<BN / 4, 256, 0, stream>>>(lraw, laug, cons);
    mean_kernel<<<BN / 256, 256, 0, stream>>>(ent, sc);
    setup_kernel<<<1, 1, 0, stream>>>(sc);
    histA_kernel<<<BN / 256, 256, 0, stream>>>(ent, histA);
    scanA_kernel<<<1, 1024, 0, stream>>>(histA, sc);
    histB_kernel<<<BN / 256, 256, 0, stream>>>(ent, sc, histBl, histBh);
    scanB_kernel<<<1, 1024, 0, stream>>>(histBl, histBh, sc);
    compact_kernel<<<BN / 256, 256, 0, stream>>>(ent, pmaxA, yhat, cons, lab0, ent0, conf0, sc,
                                                 le_cls, le_ent, le_conf, le_ord, le_src);
    topk_kernel<<<64, 256, 0, stream>>>(sc, le_cls, le_ent, le_conf, le_ord, le_w);
    cacc_kernel<<<128, 256, 0, stream>>>(sc, le_cls, le_w, le_src, W, feat, wnorm, rnorm, cacc);
    cnorm_kernel<<<CN, 256, 0, stream>>>(cacc);
    gemm_kernel<1><<<BN / BR, 256, 0, stream>>>(feat, cacc, nullptr, nullptr, nullptr, nullptr, nullptr, rnorm, out);
}

// Round 2
// 431.064 us; speedup vs baseline: 1.4793x; 1.4793x over previous
//
#include <hip/hip_runtime.h>
#include <math.h>

// ---------------- problem constants ----------------
constexpr int BN = 65536;   // batch
constexpr int DK = 512;     // feature dim
constexpr int CN = 50;      // classes
constexpr int FILTK = 10;   // per-class top-K
constexpr int BR = 64;      // rows per GEMM block
constexpr int KC = 32;      // K chunk
constexpr int AS = 36;      // LDS stride for A tile (floats)
constexpr int BS = 68;      // LDS stride for B tile (floats)
constexpr int SELB = 64;    // blocks per selection pass

// ---------------- workspace layout (u32 words) ----------------
constexpr int W_SC     = 0;                  // 64 (Scalars)
constexpr int W_H1     = 64;                 // 2048
constexpr int W_H2LO   = 2112;               // 2048
constexpr int W_H2HI   = 4160;               // 2048
constexpr int W_H3LO   = 6208;               // 1024
constexpr int W_H3HI   = 7232;               // 1024
constexpr int ZERO_WORDS = 8256;             // zeroed every call by init_kernel
constexpr int W_ENT    = ZERO_WORDS;         // BN
constexpr int W_PMAX   = W_ENT  + BN;
constexpr int W_YHAT   = W_PMAX + BN;
constexpr int W_CONS   = W_YHAT + BN;
constexpr int W_NORM   = W_CONS + BN;
constexpr int W_LAB0   = W_NORM + BN;        // 64
constexpr int W_ENT0   = W_LAB0 + 64;
constexpr int W_CONF0  = W_ENT0 + 64;
constexpr int W_WNORM  = W_CONF0 + 64;
constexpr int LE_CAP   = BN + 64;
constexpr int W_LECLS  = W_WNORM + 64;
constexpr int W_LEENT  = W_LECLS  + LE_CAP;
constexpr int W_LECONF = W_LEENT  + LE_CAP;
constexpr int W_LEORD  = W_LECONF + LE_CAP;
constexpr int W_LESRC  = W_LEORD  + LE_CAP;
constexpr int W_LEW    = W_LESRC  + LE_CAP;
constexpr int W_CENT   = W_LEW    + LE_CAP;  // 50*512

struct Scalars {
    float    sum_ent;    // atomic accum (gemm0)
    float    mean;
    float    conf_thr;
    float    frac;
    int      klo;
    int      khi;
    unsigned prefix_lo;  // grows 11 -> 22 -> 32 bits
    unsigned rank_lo;
    unsigned prefix_hi;
    unsigned rank_hi;
    float    thr;
    unsigned cnt;        // accepted count (compact)
    unsigned done1, done2, done3;
};

// monotone float<->u32 key (total order matching float compare)
__device__ __forceinline__ unsigned fkey(float f) {
    unsigned u = __float_as_uint(f);
    return (u & 0x80000000u) ? ~u : (u | 0x80000000u);
}
__device__ __forceinline__ float funkey(unsigned u) {
    return (u & 0x80000000u) ? __uint_as_float(u & 0x7fffffffu) : __uint_as_float(~u);
}

// ---------------- init: warmup stats (blocks 0..49) + workspace zeroing (blocks 50,51) ----------------
__global__ void init_kernel(const float* __restrict__ W, const float* __restrict__ bias,
                            int* __restrict__ lab0, float* __restrict__ ent0,
                            float* __restrict__ conf0, float* __restrict__ wnorm,
                            unsigned* __restrict__ wsz) {
    if (blockIdx.x >= CN) {
        for (int i = (blockIdx.x - CN) * 64 + threadIdx.x; i < ZERO_WORDS; i += 128)
            wsz[i] = 0u;
        return;
    }
    __shared__ float wrow[DK];
    const int i = blockIdx.x, l = threadIdx.x;
    float4 v0 = *(const float4*)(W + i * DK + l * 4);
    float4 v1 = *(const float4*)(W + i * DK + 256 + l * 4);
    *(float4*)(wrow + l * 4) = v0;
    *(float4*)(wrow + 256 + l * 4) = v1;
    float sq = v0.x*v0.x + v0.y*v0.y + v0.z*v0.z + v0.w*v0.w
             + v1.x*v1.x + v1.y*v1.y + v1.z*v1.z + v1.w*v1.w;
    #pragma unroll
    for (int m = 1; m < 64; m <<= 1) sq += __shfl_xor(sq, m);
    if (l == 0) wnorm[i] = sqrtf(sq);
    __syncthreads();

    float dot = -INFINITY;
    int   ai  = 0x7fffffff;
    if (l < CN) {
        const float* wj = W + l * DK;
        float d2 = 0.f;
        for (int d = 0; d < DK; d += 4) {
            float4 a  = *(const float4*)(wrow + d);
            float4 b4 = *(const float4*)(wj + d);
            d2 = fmaf(a.x, b4.x, fmaf(a.y, b4.y, fmaf(a.z, b4.z, fmaf(a.w, b4.w, d2))));
        }
        dot = d2 + bias[l];
        ai  = l;
    }
    float mx = dot; int am = ai;
    #pragma unroll
    for (int m = 32; m >= 1; m >>= 1) {
        float o = __shfl_xor(mx, m); int oi = __shfl_xor(am, m);
        if (o > mx || (o == mx && oi < am)) { mx = o; am = oi; }
    }
    float e = 0.f, te = 0.f;
    if (l < CN) { e = expf(dot - mx); te = e * (dot - mx); }
    #pragma unroll
    for (int m = 1; m < 64; m <<= 1) { e += __shfl_xor(e, m); te += __shfl_xor(te, m); }
    if (l == 0) {
        lab0[i]  = am;
        ent0[i]  = logf(e) - te / e;
        conf0[i] = 1.f / e;
    }
}

// Tiled skinny GEMM: (BN x DK) @ (CN x DK)^T, CN padded to 64 in-tile.
// MODE 0: logits epilogue (softmax stats + ent-sum atomic) + row norms + dual-view consistency
// MODE 1: sim epilogue (out = 20 * dot / max(norm,eps))
template <int MODE>
__global__ __launch_bounds__(256) void gemm_kernel(
        const float* __restrict__ A, const float* __restrict__ Bm,
        const float* __restrict__ bias,
        float* __restrict__ ent, float* __restrict__ pmaxA,
        int* __restrict__ yhat, float* __restrict__ rnorm,
        const float* __restrict__ in_norm, float* __restrict__ outp,
        const float* __restrict__ lraw, const float* __restrict__ laug,
        unsigned* __restrict__ consp, Scalars* sc) {
    __shared__ float smem[BR * AS + KC * BS];  // 17.9 KB
    float* Af = smem;
    float* Bw = smem + BR * AS;
    const int t = threadIdx.x;
    const int tx = t & 15, ty = t >> 4;
    const int row0 = blockIdx.x * BR;
    const int srow = t >> 3, sf4 = t & 7;

    // fused dual-view argmax consistency (independent of the GEMM data path)
    if (MODE == 0 && t < BR) {
        int r = row0 + t;
        const float* rp = lraw + r * CN;
        const float* ap = laug + r * CN;
        float m1 = rp[0]; int a1 = 0;
        float m2 = ap[0]; int a2 = 0;
        for (int j = 1; j < CN; j++) {
            float v1 = rp[j]; if (v1 > m1) { m1 = v1; a1 = j; }
            float v2 = ap[j]; if (v2 > m2) { m2 = v2; a2 = j; }
        }
        consp[r] = (a1 == a2) ? 1u : 0u;
    }

    float acc[4][4];
    #pragma unroll
    for (int q = 0; q < 4; q++)
        #pragma unroll
        for (int p = 0; p < 4; p++) acc[q][p] = 0.f;
    float sq0 = 0.f, sq1 = 0.f;

    for (int k0 = 0; k0 < DK; k0 += KC) {
        __syncthreads();
        float4 va0 = *(const float4*)(A + (row0 + srow) * DK + k0 + sf4 * 4);
        float4 va1 = *(const float4*)(A + (row0 + srow + 32) * DK + k0 + sf4 * 4);
        *(float4*)(Af + srow * AS + sf4 * 4) = va0;
        *(float4*)(Af + (srow + 32) * AS + sf4 * 4) = va1;
        if (MODE == 0) {
            sq0 += va0.x*va0.x + va0.y*va0.y + va0.z*va0.z + va0.w*va0.w;
            sq1 += va1.x*va1.x + va1.y*va1.y + va1.z*va1.z + va1.w*va1.w;
        }
        #pragma unroll
        for (int h = 0; h < 2; h++) {
            int c = (t >> 3) + h * 32;
            float4 vb = make_float4(0.f, 0.f, 0.f, 0.f);
            if (c < CN) vb = *(const float4*)(Bm + c * DK + k0 + sf4 * 4);
            Bw[(sf4 * 4 + 0) * BS + c] = vb.x;
            Bw[(sf4 * 4 + 1) * BS + c] = vb.y;
            Bw[(sf4 * 4 + 2) * BS + c] = vb.z;
            Bw[(sf4 * 4 + 3) * BS + c] = vb.w;
        }
        __syncthreads();
        #pragma unroll
        for (int kk = 0; kk < KC; kk += 4) {
            float4 a[4], bb[4];
            #pragma unroll
            for (int q = 0; q < 4; q++) a[q] = *(const float4*)(Af + (ty * 4 + q) * AS + kk);
            #pragma unroll
            for (int j = 0; j < 4; j++) bb[j] = *(const float4*)(Bw + (kk + j) * BS + tx * 4);
            #pragma unroll
            for (int q = 0; q < 4; q++) {
                float aq[4] = {a[q].x, a[q].y, a[q].z, a[q].w};
                #pragma unroll
                for (int j = 0; j < 4; j++) {
                    acc[q][0] = fmaf(aq[j], bb[j].x, acc[q][0]);
                    acc[q][1] = fmaf(aq[j], bb[j].y, acc[q][1]);
                    acc[q][2] = fmaf(aq[j], bb[j].z, acc[q][2]);
                    acc[q][3] = fmaf(aq[j], bb[j].w, acc[q][3]);
                }
            }
        }
    }

    if (MODE == 0) {
        float s0 = sq0, s1 = sq1;
        #pragma unroll
        for (int m = 1; m < 8; m <<= 1) { s0 += __shfl_xor(s0, m); s1 += __shfl_xor(s1, m); }
        if (sf4 == 0) { rnorm[row0 + srow] = sqrtf(s0); rnorm[row0 + srow + 32] = sqrtf(s1); }
        __syncthreads();
        float* L = smem;  // reuse as 64 x 52 logits
        #pragma unroll
        for (int q = 0; q < 4; q++) {
            int r = ty * 4 + q;
            #pragma unroll
            for (int p = 0; p < 4; p++) {
                int c = tx * 4 + p;
                if (c < CN) L[r * 52 + c] = acc[q][p] + bias[c];
            }
        }
        __syncthreads();
        if (t < BR) {
            const float* Lr = L + t * 52;
            float mx = Lr[0]; int am = 0;
            for (int j = 1; j < CN; j++) { float v = Lr[j]; if (v > mx) { mx = v; am = j; } }
            float s = 0.f, tt = 0.f;
            for (int j = 0; j < CN; j++) {
                float d = Lr[j] - mx;
                float e = expf(d);
                s += e; tt += e * d;
            }
            float ev = logf(s) - tt / s;
            ent  [row0 + t] = ev;
            pmaxA[row0 + t] = 1.f / s;
            yhat [row0 + t] = am;
            // fused mean accumulation: one atomic per block
            float es = ev;
            #pragma unroll
            for (int m = 1; m < 64; m <<= 1) es += __shfl_xor(es, m);
            if (t == 0) atomicAdd(&sc->sum_ent, es);
        }
    } else {
        #pragma unroll
        for (int q = 0; q < 4; q++) {
            int r = row0 + ty * 4 + q;
            float sc2 = 20.f / fmaxf(in_norm[r], 1e-12f);
            #pragma unroll
            for (int p = 0; p < 4; p++) {
                int c = tx * 4 + p;
                if (c < CN) outp[r * CN + c] = acc[q][p] * sc2;
            }
        }
    }
}

// ---------------- 3-pass radix select (11 / 11 / 10 bits), LDS-privatized hist + last-block scan ----------------

// pass 1: top 11 bits; last block also computes mean/q/klo/khi (setup)
__global__ __launch_bounds__(256) void sel1_kernel(const float* __restrict__ ent,
                                                   unsigned* __restrict__ H1, Scalars* sc) {
    __shared__ unsigned h[2048];
    __shared__ unsigned part[256];
    __shared__ int last;
    const int t = threadIdx.x;
    for (int b = t; b < 2048; b += 256) h[b] = 0u;
    __syncthreads();
    const int lo = blockIdx.x * (BN / SELB), hi = lo + (BN / SELB);
    for (int i = lo + t; i < hi; i += 256)
        atomicAdd(&h[fkey(ent[i]) >> 21], 1u);
    __syncthreads();
    for (int b = t; b < 2048; b += 256) if (h[b]) atomicAdd(&H1[b], h[b]);
    __threadfence();
    if (t == 0) last = (atomicAdd(&sc->done1, 1u) == SELB - 1) ? 1 : 0;
    __syncthreads();
    if (!last) return;

    for (int b = t; b < 2048; b += 256) h[b] = atomicAdd(&H1[b], 0u);
    __syncthreads();
    unsigned ps = 0;
    #pragma unroll
    for (int j = 0; j < 8; j++) ps += h[t * 8 + j];
    part[t] = ps;
    __syncthreads();
    if (t == 0) {
        float m = sc->sum_ent / (float)BN;
        sc->mean = m;
        float q = (m >= 0.45f) ? 0.25f : ((m >= 0.38f) ? 0.30f : 0.40f);
        sc->conf_thr = (m >= 0.45f) ? 0.72f : 0.62f;
        float pos = q * (float)(BN - 1);
        float flo = floorf(pos);
        sc->frac = pos - flo;
        int klo = (int)flo;
        int khi = klo + 1; if (khi > BN - 1) khi = BN - 1;
        sc->klo = klo; sc->khi = khi;
        for (int pass = 0; pass < 2; pass++) {
            unsigned k = (pass == 0) ? (unsigned)klo : (unsigned)khi;
            unsigned cum = 0; int c = 0;
            for (; c < 255; c++) { unsigned pc = part[c]; if (cum + pc > k) break; cum += pc; }
            int b = c * 8;
            for (; b < c * 8 + 7; b++) { unsigned hb = h[b]; if (cum + hb > k) break; cum += hb; }
            if (pass == 0) { sc->prefix_lo = (unsigned)b; sc->rank_lo = k - cum; }
            else           { sc->prefix_hi = (unsigned)b; sc->rank_hi = k - cum; }
        }
    }
}

// pass 2: middle 11 bits for both tracked prefixes
__global__ __launch_bounds__(256) void sel2_kernel(const float* __restrict__ ent,
                                                   unsigned* __restrict__ HLO, unsigned* __restrict__ HHI,
                                                   Scalars* sc) {
    __shared__ unsigned hlo[2048], hhi[2048];
    __shared__ unsigned plo_s[256], phi_s[256];
    __shared__ int last;
    const int t = threadIdx.x;
    const unsigned plo = sc->prefix_lo, phi = sc->prefix_hi;
    for (int b = t; b < 2048; b += 256) { hlo[b] = 0u; hhi[b] = 0u; }
    __syncthreads();
    const int lo = blockIdx.x * (BN / SELB), hi = lo + (BN / SELB);
    for (int i = lo + t; i < hi; i += 256) {
        unsigned u = fkey(ent[i]);
        unsigned d1 = u >> 21, d2 = (u >> 10) & 2047u;
        if (d1 == plo) atomicAdd(&hlo[d2], 1u);
        if (d1 == phi) atomicAdd(&hhi[d2], 1u);
    }
    __syncthreads();
    for (int b = t; b < 2048; b += 256) {
        if (hlo[b]) atomicAdd(&HLO[b], hlo[b]);
        if (hhi[b]) atomicAdd(&HHI[b], hhi[b]);
    }
    __threadfence();
    if (t == 0) last = (atomicAdd(&sc->done2, 1u) == SELB - 1) ? 1 : 0;
    __syncthreads();
    if (!last) return;

    for (int b = t; b < 2048; b += 256) { hlo[b] = atomicAdd(&HLO[b], 0u); hhi[b] = atomicAdd(&HHI[b], 0u); }
    __syncthreads();
    unsigned pl = 0, ph = 0;
    #pragma unroll
    for (int j = 0; j < 8; j++) { pl += hlo[t * 8 + j]; ph += hhi[t * 8 + j]; }
    plo_s[t] = pl; phi_s[t] = ph;
    __syncthreads();
    if (t == 0) {
        {
            unsigned k = sc->rank_lo, cum = 0; int c = 0;
            for (; c < 255; c++) { unsigned pc = plo_s[c]; if (cum + pc > k) break; cum += pc; }
            int b = c * 8;
            for (; b < c * 8 + 7; b++) { unsigned hb = hlo[b]; if (cum + hb > k) break; cum += hb; }
            sc->prefix_lo = (plo << 11) | (unsigned)b; sc->rank_lo = k - cum;
        }
        {
            unsigned k = sc->rank_hi, cum = 0; int c = 0;
            for (; c < 255; c++) { unsigned pc = phi_s[c]; if (cum + pc > k) break; cum += pc; }
            int b = c * 8;
            for (; b < c * 8 + 7; b++) { unsigned hb = hhi[b]; if (cum + hb > k) break; cum += hb; }
            sc->prefix_hi = (phi << 11) | (unsigned)b; sc->rank_hi = k - cum;
        }
    }
}

// pass 3: low 10 bits; last block computes thr = lerp(val_lo, val_hi, frac)
__global__ __launch_bounds__(256) void sel3_kernel(const float* __restrict__ ent,
                                                   unsigned* __restrict__ HLO, unsigned* __restrict__ HHI,
                                                   Scalars* sc) {
    __shared__ unsigned hlo[1024], hhi[1024];
    __shared__ unsigned plo_s[256], phi_s[256];
    __shared__ int last;
    const int t = threadIdx.x;
    const unsigned plo = sc->prefix_lo, phi = sc->prefix_hi;
    for (int b = t; b < 1024; b += 256) { hlo[b] = 0u; hhi[b] = 0u; }
    __syncthreads();
    const int lo = blockIdx.x * (BN / SELB), hi = lo + (BN / SELB);
    for (int i = lo + t; i < hi; i += 256) {
        unsigned u = fkey(ent[i]);
        unsigned p22 = u >> 10, d3 = u & 1023u;
        if (p22 == plo) atomicAdd(&hlo[d3], 1u);
        if (p22 == phi) atomicAdd(&hhi[d3], 1u);
    }
    __syncthreads();
    for (int b = t; b < 1024; b += 256) {
        if (hlo[b]) atomicAdd(&HLO[b], hlo[b]);
        if (hhi[b]) atomicAdd(&HHI[b], hhi[b]);
    }
    __threadfence();
    if (t == 0) last = (atomicAdd(&sc->done3, 1u) == SELB - 1) ? 1 : 0;
    __syncthreads();
    if (!last) return;

    for (int b = t; b < 1024; b += 256) { hlo[b] = atomicAdd(&HLO[b], 0u); hhi[b] = atomicAdd(&HHI[b], 0u); }
    __syncthreads();
    unsigned pl = 0, ph = 0;
    #pragma unroll
    for (int j = 0; j < 4; j++) { pl += hlo[t * 4 + j]; ph += hhi[t * 4 + j]; }
    plo_s[t] = pl; phi_s[t] = ph;
    __syncthreads();
    if (t == 0) {
        float vlo, vhi;
        {
            unsigned k = sc->rank_lo, cum = 0; int c = 0;
            for (; c < 255; c++) { unsigned pc = plo_s[c]; if (cum + pc > k) break; cum += pc; }
            int b = c * 4;
            for (; b < c * 4 + 3; b++) { unsigned hb = hlo[b]; if (cum + hb > k) break; cum += hb; }
            vlo = funkey((plo << 10) | (unsigned)b);
        }
        {
            unsigned k = sc->rank_hi, cum = 0; int c = 0;
            for (; c < 255; c++) { unsigned pc = phi_s[c]; if (cum + pc > k) break; cum += pc; }
            int b = c * 4;
            for (; b < c * 4 + 3; b++) { unsigned hb = hhi[b]; if (cum + hb > k) break; cum += hb; }
            vhi = funkey((phi << 10) | (unsigned)b);
        }
        sc->thr = vlo * (1.f - sc->frac) + vhi * sc->frac;
    }
}

// ---------------- gating + compaction ----------------
__global__ __launch_bounds__(256) void compact_kernel(
        const float* __restrict__ ent, const float* __restrict__ pmaxA,
        const int* __restrict__ yhat, const unsigned* __restrict__ cons,
        const int* __restrict__ lab0, const float* __restrict__ ent0,
        const float* __restrict__ conf0, Scalars* sc,
        int* le_cls, float* le_ent, float* le_conf, int* le_ord, int* le_src) {
    int i = blockIdx.x * blockDim.x + threadIdx.x;
    if (i < CN) {  // warmup entries occupy fixed slots 0..49
        le_cls[i] = lab0[i]; le_ent[i] = ent0[i]; le_conf[i] = conf0[i];
        le_ord[i] = i; le_src[i] = i;
    }
    if (i >= BN) return;
    bool m = (ent[i] <= sc->thr) && (cons[i] != 0u) && (pmaxA[i] >= sc->conf_thr);
    if (m) {
        int pos = (int)atomicAdd(&sc->cnt, 1u);
        int e = CN + pos;
        le_cls[e] = yhat[i]; le_ent[e] = ent[i]; le_conf[e] = pmaxA[i];
        le_ord[e] = CN + i;  le_src[e] = i;
    }
}

// ---------------- fused tail: per-class top-K + centroid accumulate (LDS) + normalize ----------------
__global__ __launch_bounds__(256) void tail_kernel(
        const Scalars* sc, const int* __restrict__ le_cls,
        const float* __restrict__ le_ent, const float* __restrict__ le_conf,
        const int* __restrict__ le_ord, const int* __restrict__ le_src,
        float* __restrict__ le_w,
        const float* __restrict__ W, const float* __restrict__ feat,
        const float* __restrict__ wnorm, const float* __restrict__ rnorm,
        float* __restrict__ cent) {
    __shared__ float cacc[CN * DK];  // 100 KB
    const int t = threadIdx.x;
    const int M = CN + (int)sc->cnt;

    // top-K weights (rank-by-entropy within class, stable by original index)
    for (int e = t; e < M; e += 256) {
        int c = le_cls[e]; float v = le_ent[e]; int o = le_ord[e];
        int cnt = 0;
        for (int e2 = 0; e2 < M && cnt < FILTK; e2++) {
            if (le_cls[e2] == c) {
                float v2 = le_ent[e2];
                if (v2 < v || (v2 == v && le_ord[e2] < o)) cnt++;
            }
        }
        le_w[e] = (cnt < FILTK) ? fmaxf(le_conf[e], 1e-6f) : 0.f;
    }
    for (int d = t; d < CN * DK; d += 256) cacc[d] = 0.f;
    __syncthreads();   // makes le_w (global) visible block-wide

    for (int e = 0; e < M; e++) {
        float w = le_w[e];
        if (w <= 0.f) continue;
        int src = le_src[e];
        const float* rowp = (e < CN) ? (W + src * DK) : (feat + (size_t)src * DK);
        float nrm = (e < CN) ? wnorm[src] : rnorm[src];
        float k = w / fmaxf(nrm, 1e-12f);
        float* cp = cacc + le_cls[e] * DK;
        #pragma unroll
        for (int j = 0; j < 2; j++) cp[t + j * 256] += k * rowp[t + j * 256];
    }
    __syncthreads();

    // normalize each centroid: one wave per class
    const int w64 = t >> 6, l = t & 63;
    for (int c = w64; c < CN; c += 4) {
        float s = 0.f;
        #pragma unroll
        for (int j = 0; j < 8; j++) { float v = cacc[c * DK + l + j * 64]; s = fmaf(v, v, s); }
        #pragma unroll
        for (int m = 1; m < 64; m <<= 1) s += __shfl_xor(s, m);
        float inv = 1.f / fmaxf(sqrtf(s), 1e-12f);
        #pragma unroll
        for (int j = 0; j < 8; j++) cent[c * DK + l + j * 64] = cacc[c * DK + l + j * 64] * inv;
    }
}

// ---------------- launch ----------------
extern "C" void kernel_launch(void* const* d_in, const int* in_sizes, int n_in,
                              void* d_out, int out_size, void* d_ws, size_t ws_size,
                              hipStream_t stream) {
    const float* feat = (const float*)d_in[0];
    const float* lraw = (const float*)d_in[1];
    const float* laug = (const float*)d_in[2];
    const float* W    = (const float*)d_in[3];
    const float* bias = (const float*)d_in[4];
    float* out = (float*)d_out;

    unsigned* wsw    = (unsigned*)d_ws;
    Scalars*  sc     = (Scalars*)(wsw + W_SC);
    unsigned* H1     = wsw + W_H1;
    unsigned* H2LO   = wsw + W_H2LO;
    unsigned* H2HI   = wsw + W_H2HI;
    unsigned* H3LO   = wsw + W_H3LO;
    unsigned* H3HI   = wsw + W_H3HI;
    float*    ent    = (float*)(wsw + W_ENT);
    float*    pmaxA  = (float*)(wsw + W_PMAX);
    int*      yhat   = (int*)(wsw + W_YHAT);
    unsigned* cons   = wsw + W_CONS;
    float*    rnorm  = (float*)(wsw + W_NORM);
    int*      lab0   = (int*)(wsw + W_LAB0);
    float*    ent0   = (float*)(wsw + W_ENT0);
    float*    conf0  = (float*)(wsw + W_CONF0);
    float*    wnorm  = (float*)(wsw + W_WNORM);
    int*      le_cls = (int*)(wsw + W_LECLS);
    float*    le_ent = (float*)(wsw + W_LEENT);
    float*    le_conf= (float*)(wsw + W_LECONF);
    int*      le_ord = (int*)(wsw + W_LEORD);
    int*      le_src = (int*)(wsw + W_LESRC);
    float*    le_w   = (float*)(wsw + W_LEW);
    float*    cent   = (float*)(wsw + W_CENT);

    init_kernel<<<CN + 2, 64, 0, stream>>>(W, bias, lab0, ent0, conf0, wnorm, wsw);
    gemm_kernel<0><<<BN / BR, 256, 0, stream>>>(feat, W, bias, ent, pmaxA, yhat, rnorm,
                                                nullptr, nullptr, lraw, laug, cons, sc);
    sel1_kernel<<<SELB, 256, 0, stream>>>(ent, H1, sc);
    sel2_kernel<<<SELB, 256, 0, stream>>>(ent, H2LO, H2HI, sc);
    sel3_kernel<<<SELB, 256, 0, stream>>>(ent, H3LO, H3HI, sc);
    compact_kernel<<<BN / 256, 256, 0, stream>>>(ent, pmaxA, yhat, cons, lab0, ent0, conf0, sc,
                                                 le_cls, le_ent, le_conf, le_ord, le_src);
    tail_kernel<<<1, 256, 0, stream>>>(sc, le_cls, le_ent, le_conf, le_ord, le_src, le_w,
                                       W, feat, wnorm, rnorm, cent);
    gemm_kernel<1><<<BN / BR, 256, 0, stream>>>(feat, cent, nullptr, nullptr, nullptr, nullptr,
                                                nullptr, rnorm, out, nullptr, nullptr, nullptr, sc);
}

// Round 3
// 345.598 us; speedup vs baseline: 1.8451x; 1.2473x over previous
//
#include <hip/hip_runtime.h>
#include <math.h>

// ---------------- problem constants ----------------
constexpr int BN = 65536;   // batch
constexpr int DK = 512;     // feature dim
constexpr int CN = 50;      // classes
constexpr int FILTK = 10;   // per-class top-K
constexpr int MB = 128;     // rows per GEMM block
constexpr int NKS = DK / 32;// 16 K-steps
constexpr int SELB = 64;    // blocks per selection pass
constexpr int CAP = 6144;   // per-class LDS entry cap in tail

typedef __attribute__((ext_vector_type(8))) short short8;
typedef __attribute__((ext_vector_type(4))) float f4;

// ---------------- workspace layout (u32 words) ----------------
constexpr int W_SC     = 0;                  // 64 (Scalars)
constexpr int W_H1     = 64;                 // 2048
constexpr int W_H2LO   = 2112;               // 2048
constexpr int W_H2HI   = 4160;               // 2048
constexpr int W_H3LO   = 6208;               // 1024
constexpr int W_H3HI   = 7232;               // 1024
constexpr int ZERO_WORDS = 8256;             // zeroed every call by init_kernel
constexpr int W_WFH    = 8256;               // W frags hi: 32768 ushort = 16384 words
constexpr int W_WFL    = W_WFH + 16384;
constexpr int W_CFH    = W_WFL + 16384;      // centroid frags hi
constexpr int W_CFL    = W_CFH + 16384;
constexpr int W_ENT    = W_CFL + 16384;      // BN
constexpr int W_PMAX   = W_ENT  + BN;
constexpr int W_YHAT   = W_PMAX + BN;
constexpr int W_CONS   = W_YHAT + BN;
constexpr int W_NORM   = W_CONS + BN;
constexpr int W_LAB0   = W_NORM + BN;        // 64
constexpr int W_ENT0   = W_LAB0 + 64;
constexpr int W_CONF0  = W_ENT0 + 64;
constexpr int W_WNORM  = W_CONF0 + 64;
constexpr int LE_CAP   = BN + 64;
constexpr int W_LECLS  = W_WNORM + 64;
constexpr int W_LEENT  = W_LECLS  + LE_CAP;
constexpr int W_LECONF = W_LEENT  + LE_CAP;
constexpr int W_LEORD  = W_LECONF + LE_CAP;
constexpr int W_LESRC  = W_LEORD  + LE_CAP;

struct Scalars {
    float    sum_ent;
    float    mean;
    float    conf_thr;
    float    frac;
    int      klo;
    int      khi;
    unsigned prefix_lo;
    unsigned rank_lo;
    unsigned prefix_hi;
    unsigned rank_hi;
    float    thr;
    unsigned cnt;
    unsigned done1, done2, done3;
};

// monotone float<->u32 key
__device__ __forceinline__ unsigned fkey(float f) {
    unsigned u = __float_as_uint(f);
    return (u & 0x80000000u) ? ~u : (u | 0x80000000u);
}
__device__ __forceinline__ float funkey(unsigned u) {
    return (u & 0x80000000u) ? __uint_as_float(u & 0x7fffffffu) : __uint_as_float(~u);
}

// bf16 split helpers (RNE)
__device__ __forceinline__ short bf16h(float x) {
    unsigned u = __float_as_uint(x);
    return (short)((u + 0x7fffu + ((u >> 16) & 1u)) >> 16);
}
__device__ __forceinline__ float bf16tof(short h) {
    return __uint_as_float(((unsigned)(unsigned short)h) << 16);
}
__device__ __forceinline__ void cvt8(const float* a, short8& h, short8& l) {
    #pragma unroll
    for (int j = 0; j < 8; j++) {
        short hh = bf16h(a[j]);
        h[j] = hh;
        l[j] = bf16h(a[j] - bf16tof(hh));
    }
}
// frag element index: [ks][ntile][lane=(n&15)+16q][j]
__device__ __forceinline__ int fragidx(int ks, int n, int q, int j) {
    return ks * 2048 + (n >> 4) * 512 + ((n & 15) + 16 * q) * 8 + j;
}

// ---------------- init: W frag rows (blocks 0..63) + warmup stats (blocks 0..49) + zero (64,65) ----------------
__global__ void init_kernel(const float* __restrict__ W, const float* __restrict__ bias,
                            int* __restrict__ lab0, float* __restrict__ ent0,
                            float* __restrict__ conf0, float* __restrict__ wnorm,
                            unsigned* __restrict__ wsz,
                            short* __restrict__ wfh, short* __restrict__ wfl) {
    const int b = blockIdx.x, l = threadIdx.x;
    if (b >= 64) {
        for (int i = (b - 64) * 64 + l; i < ZERO_WORDS; i += 128) wsz[i] = 0u;
        return;
    }
    {   // frag duty for row b (thread l covers k = l*8 .. l*8+7 -> ks=l>>2, q=l&3, j=0..7)
        int ks = l >> 2, q = l & 3;
        int dst = fragidx(ks, b, q, 0);
        if (b < CN) {
            const float* wp = W + b * DK + l * 8;
            f4 x = *(const f4*)wp, y = *(const f4*)(wp + 4);
            float a8[8] = {x[0], x[1], x[2], x[3], y[0], y[1], y[2], y[3]};
            short8 h, lo2; cvt8(a8, h, lo2);
            *(short8*)(wfh + dst) = h;
            *(short8*)(wfl + dst) = lo2;
        } else {
            short8 z; 
            #pragma unroll
            for (int j = 0; j < 8; j++) z[j] = 0;
            *(short8*)(wfh + dst) = z;
            *(short8*)(wfl + dst) = z;
        }
    }
    if (b >= CN) return;

    __shared__ float wrow[DK];
    const int i = b;
    f4 v0 = *(const f4*)(W + i * DK + l * 4);
    f4 v1 = *(const f4*)(W + i * DK + 256 + l * 4);
    *(f4*)(wrow + l * 4) = v0;
    *(f4*)(wrow + 256 + l * 4) = v1;
    float sq = v0[0]*v0[0] + v0[1]*v0[1] + v0[2]*v0[2] + v0[3]*v0[3]
             + v1[0]*v1[0] + v1[1]*v1[1] + v1[2]*v1[2] + v1[3]*v1[3];
    #pragma unroll
    for (int m = 1; m < 64; m <<= 1) sq += __shfl_xor(sq, m);
    if (l == 0) wnorm[i] = sqrtf(sq);
    __syncthreads();

    float dot = -INFINITY;
    int   ai  = 0x7fffffff;
    if (l < CN) {
        const float* wj = W + l * DK;
        float d2 = 0.f;
        for (int d = 0; d < DK; d += 4) {
            f4 a = *(const f4*)(wrow + d);
            f4 b4 = *(const f4*)(wj + d);
            d2 = fmaf(a[0], b4[0], fmaf(a[1], b4[1], fmaf(a[2], b4[2], fmaf(a[3], b4[3], d2))));
        }
        dot = d2 + bias[l];
        ai  = l;
    }
    float mx = dot; int am = ai;
    #pragma unroll
    for (int m = 32; m >= 1; m >>= 1) {
        float o = __shfl_xor(mx, m); int oi = __shfl_xor(am, m);
        if (o > mx || (o == mx && oi < am)) { mx = o; am = oi; }
    }
    float e = 0.f, te = 0.f;
    if (l < CN) { e = expf(dot - mx); te = e * (dot - mx); }
    #pragma unroll
    for (int m = 1; m < 64; m <<= 1) { e += __shfl_xor(e, m); te += __shfl_xor(te, m); }
    if (l == 0) {
        lab0[i]  = am;
        ent0[i]  = logf(e) - te / e;
        conf0[i] = 1.f / e;
    }
}

// ---------------- MFMA split-bf16 GEMM: (BN x DK) @ frag(64 x DK)^T ----------------
// MODE 0: logits -> softmax stats + row norms + dual-view consistency + ent-sum
// MODE 1: out = 20 * dot / max(rnorm, eps)
template <int MODE>
__global__ __launch_bounds__(256) void gemm_kernel(
        const float* __restrict__ feat,
        const short* __restrict__ bfh, const short* __restrict__ bfl,
        const float* __restrict__ bias,
        float* __restrict__ ent, float* __restrict__ pmaxA,
        int* __restrict__ yhat, float* __restrict__ rnorm,
        const float* __restrict__ lraw, const float* __restrict__ laug,
        unsigned* __restrict__ consp, Scalars* sc, float* __restrict__ outp) {
    constexpr int LSZ = (MODE == 0) ? MB * 65 : 4;
    __shared__ float L[LSZ];
    const int t = threadIdx.x;
    const int w = t >> 6, lane = t & 63, m = lane & 15, q = lane >> 4;
    const int rb = blockIdx.x * MB + w * 32;

    f4 acc[2][4];
    #pragma unroll
    for (int mt = 0; mt < 2; mt++)
        #pragma unroll
        for (int nt = 0; nt < 4; nt++) acc[mt][nt] = (f4){0.f, 0.f, 0.f, 0.f};
    float sq[2] = {0.f, 0.f};

    for (int ks = 0; ks < NKS; ks++) {
        short8 ah[2], al[2];
        #pragma unroll
        for (int mt = 0; mt < 2; mt++) {
            const float* ap = feat + (size_t)(rb + mt * 16 + m) * DK + ks * 32 + q * 8;
            f4 x = *(const f4*)ap;
            f4 y = *(const f4*)(ap + 4);
            float a8[8] = {x[0], x[1], x[2], x[3], y[0], y[1], y[2], y[3]};
            if (MODE == 0) {
                sq[mt] += x[0]*x[0] + x[1]*x[1] + x[2]*x[2] + x[3]*x[3]
                        + y[0]*y[0] + y[1]*y[1] + y[2]*y[2] + y[3]*y[3];
            }
            cvt8(a8, ah[mt], al[mt]);
        }
        short8 bh[4], bl[4];
        #pragma unroll
        for (int nt = 0; nt < 4; nt++) {
            int off = ks * 2048 + nt * 512 + lane * 8;
            bh[nt] = *(const short8*)(bfh + off);
            bl[nt] = *(const short8*)(bfl + off);
        }
        #pragma unroll
        for (int mt = 0; mt < 2; mt++)
            #pragma unroll
            for (int nt = 0; nt < 4; nt++) {
                acc[mt][nt] = __builtin_amdgcn_mfma_f32_16x16x32_bf16(ah[mt], bh[nt], acc[mt][nt], 0, 0, 0);
                acc[mt][nt] = __builtin_amdgcn_mfma_f32_16x16x32_bf16(al[mt], bh[nt], acc[mt][nt], 0, 0, 0);
                acc[mt][nt] = __builtin_amdgcn_mfma_f32_16x16x32_bf16(ah[mt], bl[nt], acc[mt][nt], 0, 0, 0);
            }
    }

    if (MODE == 0) {
        // row norms: lane (m,q) holds disjoint k-slices of row rb+mt*16+m
        #pragma unroll
        for (int mt = 0; mt < 2; mt++) {
            float s = sq[mt];
            s += __shfl_xor(s, 16);
            s += __shfl_xor(s, 32);
            if (q == 0) rnorm[rb + mt * 16 + m] = sqrtf(s);
        }
        // logits to LDS (C layout: col = nt*16+m, row = q*4+reg)
        float bc[4];
        #pragma unroll
        for (int nt = 0; nt < 4; nt++) { int c = nt * 16 + m; bc[nt] = (c < CN) ? bias[c] : 0.f; }
        #pragma unroll
        for (int mt = 0; mt < 2; mt++)
            #pragma unroll
            for (int nt = 0; nt < 4; nt++)
                #pragma unroll
                for (int r = 0; r < 4; r++) {
                    int row = w * 32 + mt * 16 + q * 4 + r;
                    L[row * 65 + nt * 16 + m] = acc[mt][nt][r] + bc[nt];
                }
        __syncthreads();
        if (t < MB) {
            int grow = blockIdx.x * MB + t;
            const float* Lr = L + t * 65;
            float mx = Lr[0]; int am = 0;
            #pragma unroll 10
            for (int j = 1; j < CN; j++) { float v = Lr[j]; if (v > mx) { mx = v; am = j; } }
            float s = 0.f, tt = 0.f;
            for (int j = 0; j < CN; j++) {
                float d = Lr[j] - mx;
                float e = expf(d);
                s += e; tt += e * d;
            }
            float ev = logf(s) - tt / s;
            ent  [grow] = ev;
            pmaxA[grow] = 1.f / s;
            yhat [grow] = am;
            // dual-view consistency
            const float* rp  = lraw + (size_t)grow * CN;
            const float* apg = laug + (size_t)grow * CN;
            float m1 = rp[0];  int a1 = 0;
            float m2 = apg[0]; int a2 = 0;
            #pragma unroll 10
            for (int j = 1; j < CN; j++) {
                float v1 = rp[j];  if (v1 > m1) { m1 = v1; a1 = j; }
                float v2 = apg[j]; if (v2 > m2) { m2 = v2; a2 = j; }
            }
            consp[grow] = (a1 == a2) ? 1u : 0u;
            // ent-sum: one atomic per wave
            float es = ev;
            #pragma unroll
            for (int mk = 1; mk < 64; mk <<= 1) es += __shfl_xor(es, mk);
            if ((t & 63) == 0) atomicAdd(&sc->sum_ent, es);
        }
    } else {
        #pragma unroll
        for (int mt = 0; mt < 2; mt++)
            #pragma unroll
            for (int r = 0; r < 4; r++) {
                int grow = rb + mt * 16 + q * 4 + r;
                float s = 20.f / fmaxf(rnorm[grow], 1e-12f);
                #pragma unroll
                for (int nt = 0; nt < 4; nt++) {
                    int c = nt * 16 + m;
                    if (c < CN) outp[(size_t)grow * CN + c] = acc[mt][nt][r] * s;
                }
            }
    }
}

// ---------------- 3-pass radix select (11/11/10 bits) ----------------
__global__ __launch_bounds__(256) void sel1_kernel(const float* __restrict__ ent,
                                                   unsigned* __restrict__ H1, Scalars* sc) {
    __shared__ unsigned h[2048];
    __shared__ unsigned part[256];
    __shared__ int last;
    const int t = threadIdx.x;
    for (int b = t; b < 2048; b += 256) h[b] = 0u;
    __syncthreads();
    const int lo = blockIdx.x * (BN / SELB), hi = lo + (BN / SELB);
    for (int i = lo + t; i < hi; i += 256)
        atomicAdd(&h[fkey(ent[i]) >> 21], 1u);
    __syncthreads();
    for (int b = t; b < 2048; b += 256) if (h[b]) atomicAdd(&H1[b], h[b]);
    __threadfence();
    if (t == 0) last = (atomicAdd(&sc->done1, 1u) == SELB - 1) ? 1 : 0;
    __syncthreads();
    if (!last) return;

    for (int b = t; b < 2048; b += 256) h[b] = atomicAdd(&H1[b], 0u);
    __syncthreads();
    unsigned ps = 0;
    #pragma unroll
    for (int j = 0; j < 8; j++) ps += h[t * 8 + j];
    part[t] = ps;
    __syncthreads();
    if (t == 0) {
        float m = sc->sum_ent / (float)BN;
        sc->mean = m;
        float q = (m >= 0.45f) ? 0.25f : ((m >= 0.38f) ? 0.30f : 0.40f);
        sc->conf_thr = (m >= 0.45f) ? 0.72f : 0.62f;
        float pos = q * (float)(BN - 1);
        float flo = floorf(pos);
        sc->frac = pos - flo;
        int klo = (int)flo;
        int khi = klo + 1; if (khi > BN - 1) khi = BN - 1;
        sc->klo = klo; sc->khi = khi;
        for (int pass = 0; pass < 2; pass++) {
            unsigned k = (pass == 0) ? (unsigned)klo : (unsigned)khi;
            unsigned cum = 0; int c = 0;
            for (; c < 255; c++) { unsigned pc = part[c]; if (cum + pc > k) break; cum += pc; }
            int b = c * 8;
            for (; b < c * 8 + 7; b++) { unsigned hb = h[b]; if (cum + hb > k) break; cum += hb; }
            if (pass == 0) { sc->prefix_lo = (unsigned)b; sc->rank_lo = k - cum; }
            else           { sc->prefix_hi = (unsigned)b; sc->rank_hi = k - cum; }
        }
    }
}

__global__ __launch_bounds__(256) void sel2_kernel(const float* __restrict__ ent,
                                                   unsigned* __restrict__ HLO, unsigned* __restrict__ HHI,
                                                   Scalars* sc) {
    __shared__ unsigned hlo[2048], hhi[2048];
    __shared__ unsigned plo_s[256], phi_s[256];
    __shared__ int last;
    const int t = threadIdx.x;
    const unsigned plo = sc->prefix_lo, phi = sc->prefix_hi;
    for (int b = t; b < 2048; b += 256) { hlo[b] = 0u; hhi[b] = 0u; }
    __syncthreads();
    const int lo = blockIdx.x * (BN / SELB), hi = lo + (BN / SELB);
    for (int i = lo + t; i < hi; i += 256) {
        unsigned u = fkey(ent[i]);
        unsigned d1 = u >> 21, d2 = (u >> 10) & 2047u;
        if (d1 == plo) atomicAdd(&hlo[d2], 1u);
        if (d1 == phi) atomicAdd(&hhi[d2], 1u);
    }
    __syncthreads();
    for (int b = t; b < 2048; b += 256) {
        if (hlo[b]) atomicAdd(&HLO[b], hlo[b]);
        if (hhi[b]) atomicAdd(&HHI[b], hhi[b]);
    }
    __threadfence();
    if (t == 0) last = (atomicAdd(&sc->done2, 1u) == SELB - 1) ? 1 : 0;
    __syncthreads();
    if (!last) return;

    for (int b = t; b < 2048; b += 256) { hlo[b] = atomicAdd(&HLO[b], 0u); hhi[b] = atomicAdd(&HHI[b], 0u); }
    __syncthreads();
    unsigned pl = 0, ph = 0;
    #pragma unroll
    for (int j = 0; j < 8; j++) { pl += hlo[t * 8 + j]; ph += hhi[t * 8 + j]; }
    plo_s[t] = pl; phi_s[t] = ph;
    __syncthreads();
    if (t == 0) {
        {
            unsigned k = sc->rank_lo, cum = 0; int c = 0;
            for (; c < 255; c++) { unsigned pc = plo_s[c]; if (cum + pc > k) break; cum += pc; }
            int b = c * 8;
            for (; b < c * 8 + 7; b++) { unsigned hb = hlo[b]; if (cum + hb > k) break; cum += hb; }
            sc->prefix_lo = (plo << 11) | (unsigned)b; sc->rank_lo = k - cum;
        }
        {
            unsigned k = sc->rank_hi, cum = 0; int c = 0;
            for (; c < 255; c++) { unsigned pc = phi_s[c]; if (cum + pc > k) break; cum += pc; }
            int b = c * 8;
            for (; b < c * 8 + 7; b++) { unsigned hb = hhi[b]; if (cum + hb > k) break; cum += hb; }
            sc->prefix_hi = (phi << 11) | (unsigned)b; sc->rank_hi = k - cum;
        }
    }
}

__global__ __launch_bounds__(256) void sel3_kernel(const float* __restrict__ ent,
                                                   unsigned* __restrict__ HLO, unsigned* __restrict__ HHI,
                                                   Scalars* sc) {
    __shared__ unsigned hlo[1024], hhi[1024];
    __shared__ unsigned plo_s[256], phi_s[256];
    __shared__ int last;
    const int t = threadIdx.x;
    const unsigned plo = sc->prefix_lo, phi = sc->prefix_hi;
    for (int b = t; b < 1024; b += 256) { hlo[b] = 0u; hhi[b] = 0u; }
    __syncthreads();
    const int lo = blockIdx.x * (BN / SELB), hi = lo + (BN / SELB);
    for (int i = lo + t; i < hi; i += 256) {
        unsigned u = fkey(ent[i]);
        unsigned p22 = u >> 10, d3 = u & 1023u;
        if (p22 == plo) atomicAdd(&hlo[d3], 1u);
        if (p22 == phi) atomicAdd(&hhi[d3], 1u);
    }
    __syncthreads();
    for (int b = t; b < 1024; b += 256) {
        if (hlo[b]) atomicAdd(&HLO[b], hlo[b]);
        if (hhi[b]) atomicAdd(&HHI[b], hhi[b]);
    }
    __threadfence();
    if (t == 0) last = (atomicAdd(&sc->done3, 1u) == SELB - 1) ? 1 : 0;
    __syncthreads();
    if (!last) return;

    for (int b = t; b < 1024; b += 256) { hlo[b] = atomicAdd(&HLO[b], 0u); hhi[b] = atomicAdd(&HHI[b], 0u); }
    __syncthreads();
    unsigned pl = 0, ph = 0;
    #pragma unroll
    for (int j = 0; j < 4; j++) { pl += hlo[t * 4 + j]; ph += hhi[t * 4 + j]; }
    plo_s[t] = pl; phi_s[t] = ph;
    __syncthreads();
    if (t == 0) {
        float vlo, vhi;
        {
            unsigned k = sc->rank_lo, cum = 0; int c = 0;
            for (; c < 255; c++) { unsigned pc = plo_s[c]; if (cum + pc > k) break; cum += pc; }
            int b = c * 4;
            for (; b < c * 4 + 3; b++) { unsigned hb = hlo[b]; if (cum + hb > k) break; cum += hb; }
            vlo = funkey((plo << 10) | (unsigned)b);
        }
        {
            unsigned k = sc->rank_hi, cum = 0; int c = 0;
            for (; c < 255; c++) { unsigned pc = phi_s[c]; if (cum + pc > k) break; cum += pc; }
            int b = c * 4;
            for (; b < c * 4 + 3; b++) { unsigned hb = hhi[b]; if (cum + hb > k) break; cum += hb; }
            vhi = funkey((phi << 10) | (unsigned)b);
        }
        sc->thr = vlo * (1.f - sc->frac) + vhi * sc->frac;
    }
}

// ---------------- gating + compaction ----------------
__global__ __launch_bounds__(256) void compact_kernel(
        const float* __restrict__ ent, const float* __restrict__ pmaxA,
        const int* __restrict__ yhat, const unsigned* __restrict__ cons,
        const int* __restrict__ lab0, const float* __restrict__ ent0,
        const float* __restrict__ conf0, Scalars* sc,
        int* le_cls, float* le_ent, float* le_conf, int* le_ord, int* le_src) {
    int i = blockIdx.x * blockDim.x + threadIdx.x;
    if (i < CN) {
        le_cls[i] = lab0[i]; le_ent[i] = ent0[i]; le_conf[i] = conf0[i];
        le_ord[i] = i; le_src[i] = i;
    }
    if (i >= BN) return;
    bool m = (ent[i] <= sc->thr) && (cons[i] != 0u) && (pmaxA[i] >= sc->conf_thr);
    if (m) {
        int pos = (int)atomicAdd(&sc->cnt, 1u);
        int e = CN + pos;
        le_cls[e] = yhat[i]; le_ent[e] = ent[i]; le_conf[e] = pmaxA[i];
        le_ord[e] = CN + i;  le_src[e] = i;
    }
}

// ---------------- class-parallel tail: top-K + centroid + normalize + frag-ize ----------------
__global__ __launch_bounds__(256) void tail2_kernel(
        const Scalars* sc, const int* __restrict__ le_cls,
        const float* __restrict__ le_ent, const float* __restrict__ le_conf,
        const int* __restrict__ le_ord, const int* __restrict__ le_src,
        const float* __restrict__ W, const float* __restrict__ feat,
        const float* __restrict__ wnorm, const float* __restrict__ rnorm,
        short* __restrict__ cfh, short* __restrict__ cfl) {
    const int c = blockIdx.x, t = threadIdx.x;
    if (c >= CN) {   // zero the pad frag rows (50..63)
        for (int idx = t; idx < 512; idx += 256) {
            int ks = idx >> 5, rem = idx & 31, qq = rem >> 3, jj = rem & 7;
            int dst = fragidx(ks, c, qq, jj);
            cfh[dst] = 0; cfl[dst] = 0;
        }
        return;
    }
    __shared__ float sent[CAP];
    __shared__ int   sord[CAP];
    __shared__ float sconf[CAP];
    __shared__ int   ssrc[CAP];
    __shared__ float wk[CAP];
    __shared__ float accv[DK];
    __shared__ float red[4];
    __shared__ int   mc_s;
    if (t == 0) mc_s = 0;
    for (int d = t; d < DK; d += 256) accv[d] = 0.f;
    __syncthreads();
    const int M = CN + (int)sc->cnt;
    for (int e = t; e < M; e += 256) {
        if (le_cls[e] == c) {
            int i = atomicAdd(&mc_s, 1);
            if (i < CAP) { sent[i] = le_ent[e]; sord[i] = le_ord[e]; sconf[i] = le_conf[e]; ssrc[i] = le_src[e]; }
        }
    }
    __syncthreads();
    int mc = min(mc_s, CAP);
    for (int i = t; i < mc; i += 256) {
        float v = sent[i]; int o = sord[i]; int r = 0;
        for (int j = 0; j < mc && r < FILTK; j++)
            if (sent[j] < v || (sent[j] == v && sord[j] < o)) r++;
        wk[i] = (r < FILTK) ? fmaxf(sconf[i], 1e-6f) : 0.f;
    }
    __syncthreads();
    for (int i = 0; i < mc; i++) {
        float wgt = wk[i];
        if (wgt <= 0.f) continue;
        int src = ssrc[i];
        bool warm = sord[i] < CN;
        const float* rowp = warm ? (W + src * DK) : (feat + (size_t)src * DK);
        float nr = warm ? wnorm[src] : rnorm[src];
        float k = wgt / fmaxf(nr, 1e-12f);
        for (int d = t; d < DK; d += 256) accv[d] += k * rowp[d];
    }
    __syncthreads();
    float s = 0.f;
    for (int d = t; d < DK; d += 256) { float v = accv[d]; s = fmaf(v, v, s); }
    #pragma unroll
    for (int mk = 1; mk < 64; mk <<= 1) s += __shfl_xor(s, mk);
    if ((t & 63) == 0) red[t >> 6] = s;
    __syncthreads();
    float inv = 1.f / fmaxf(sqrtf(red[0] + red[1] + red[2] + red[3]), 1e-12f);
    for (int k = t; k < DK; k += 256) {
        float v = accv[k] * inv;
        short hh = bf16h(v);
        short ll = bf16h(v - bf16tof(hh));
        int ks = k >> 5, kk = k & 31, qq = kk >> 3, jj = kk & 7;
        int dst = fragidx(ks, c, qq, jj);
        cfh[dst] = hh; cfl[dst] = ll;
    }
}

// ---------------- launch ----------------
extern "C" void kernel_launch(void* const* d_in, const int* in_sizes, int n_in,
                              void* d_out, int out_size, void* d_ws, size_t ws_size,
                              hipStream_t stream) {
    const float* feat = (const float*)d_in[0];
    const float* lraw = (const float*)d_in[1];
    const float* laug = (const float*)d_in[2];
    const float* W    = (const float*)d_in[3];
    const float* bias = (const float*)d_in[4];
    float* out = (float*)d_out;

    unsigned* wsw    = (unsigned*)d_ws;
    Scalars*  sc     = (Scalars*)(wsw + W_SC);
    unsigned* H1     = wsw + W_H1;
    unsigned* H2LO   = wsw + W_H2LO;
    unsigned* H2HI   = wsw + W_H2HI;
    unsigned* H3LO   = wsw + W_H3LO;
    unsigned* H3HI   = wsw + W_H3HI;
    short*    wfh    = (short*)(wsw + W_WFH);
    short*    wfl    = (short*)(wsw + W_WFL);
    short*    cfh    = (short*)(wsw + W_CFH);
    short*    cfl    = (short*)(wsw + W_CFL);
    float*    ent    = (float*)(wsw + W_ENT);
    float*    pmaxA  = (float*)(wsw + W_PMAX);
    int*      yhat   = (int*)(wsw + W_YHAT);
    unsigned* cons   = wsw + W_CONS;
    float*    rnorm  = (float*)(wsw + W_NORM);
    int*      lab0   = (int*)(wsw + W_LAB0);
    float*    ent0   = (float*)(wsw + W_ENT0);
    float*    conf0  = (float*)(wsw + W_CONF0);
    float*    wnorm  = (float*)(wsw + W_WNORM);
    int*      le_cls = (int*)(wsw + W_LECLS);
    float*    le_ent = (float*)(wsw + W_LEENT);
    float*    le_conf= (float*)(wsw + W_LECONF);
    int*      le_ord = (int*)(wsw + W_LEORD);
    int*      le_src = (int*)(wsw + W_LESRC);

    init_kernel<<<66, 64, 0, stream>>>(W, bias, lab0, ent0, conf0, wnorm, wsw, wfh, wfl);
    gemm_kernel<0><<<BN / MB, 256, 0, stream>>>(feat, wfh, wfl, bias, ent, pmaxA, yhat, rnorm,
                                                lraw, laug, cons, sc, nullptr);
    sel1_kernel<<<SELB, 256, 0, stream>>>(ent, H1, sc);
    sel2_kernel<<<SELB, 256, 0, stream>>>(ent, H2LO, H2HI, sc);
    sel3_kernel<<<SELB, 256, 0, stream>>>(ent, H3LO, H3HI, sc);
    compact_kernel<<<BN / 256, 256, 0, stream>>>(ent, pmaxA, yhat, cons, lab0, ent0, conf0, sc,
                                                 le_cls, le_ent, le_conf, le_ord, le_src);
    tail2_kernel<<<64, 256, 0, stream>>>(sc, le_cls, le_ent, le_conf, le_ord, le_src,
                                         W, feat, wnorm, rnorm, cfh, cfl);
    gemm_kernel<1><<<BN / MB, 256, 0, stream>>>(feat, cfh, cfl, nullptr, nullptr, nullptr, nullptr, rnorm,
                                                nullptr, nullptr, nullptr, sc, out);
}